// Round 5
// baseline (2644.994 us; speedup 1.0000x reference)
//
#include <hip/hip_runtime.h>
#include <math.h>

typedef __bf16 bf16_t;
typedef __bf16 bf16x8 __attribute__((ext_vector_type(8)));
typedef float  f32x4  __attribute__((ext_vector_type(4)));

__device__ __forceinline__ void gl2lds16(const void* g, void* l) {
  __builtin_amdgcn_global_load_lds((__attribute__((address_space(1))) void*)g,
                                   (__attribute__((address_space(3))) void*)l,
                                   16, 0, 0);
}

#define MFMA16(a, b, c) __builtin_amdgcn_mfma_f32_16x16x32_bf16(a, b, c, 0, 0, 0)

// ---------------------------------------------------------------------------
// 256x256 tile, BK=64, 8 waves (2M x 4N), 128 KiB LDS (2 buffers), minimum
// 2-phase pipeline (T3 recipe): stage(t+1) at top of iter; compiler-scheduled
// ds_read + 64 MFMA body (two m-half sub-bodies to bound VGPR pressure);
// ONE __syncthreads() (vmcnt+lgkm drain + barrier) per K-tile. T2 swizzle
// byte ^= (row&7)<<4 on both sides (pre-swizzled global source, swizzled
// ds_read col) -> bank-conflict-free (verified 0 in round 4).
// C = A * B^T. MODE 0: fused QKV epilogue (seg = n0>>11: 0->q=sigmoid,
// 1->k=sigmoid(-v) + g=logsigmoid(v), 2->v). MODE 1: f32 passthrough out.
// ---------------------------------------------------------------------------
template<int MODE>
__global__ __launch_bounds__(512, 1)
void gemm256(const bf16_t* __restrict__ A, const bf16_t* __restrict__ Bw,
             bf16_t* __restrict__ oq, bf16_t* __restrict__ okk,
             bf16_t* __restrict__ ov, float* __restrict__ og,
             float* __restrict__ of, int M, int N, int K)
{
  extern __shared__ __align__(16) char smem[];
  const int tt = threadIdx.x;
  const int wave = tt >> 6, lane = tt & 63;
  const int wm = wave >> 2, wn = wave & 3;
  const int nbn = N >> 8;
  const int m0 = (int)(blockIdx.x / nbn) << 8;
  const int n0 = (int)(blockIdx.x % nbn) << 8;
  const int l15 = lane & 15, lq = lane >> 4;

  // swizzled ds_read column terms (bytes): col ^ ((row&7)<<4); row&7 == lane&7
  const int tk0 = (lq * 16) ^ ((lane & 7) << 4);
  const int tk1 = (64 + lq * 16) ^ ((lane & 7) << 4);
  const int aRow = (wm * 128 + l15) * 128;   // byte base of lane's A row
  const int bRow = (wn * 64  + l15) * 128;   // byte base of lane's B row

  // staging: thread t covers LDS linear bytes t*16 + i*8192 of a 32KB panel
  // -> row = (t>>3)+i*64, chunk = (t&7)*16.  Pre-swizzled global source col.
  const int srow = tt >> 3;
  const int scol = ((tt & 7) * 8) ^ ((srow & 7) * 8);      // elements
  const bf16_t* pA = A  + (size_t)(m0 + srow) * K + scol;
  const bf16_t* pB = Bw + (size_t)(n0 + srow) * K + scol;
  const size_t rstep = (size_t)64 * K;

  f32x4 acc[8][4] = {};
  const int T = K >> 6;

  auto stage = [&](int t, int sl) {
    const int kt = t << 6;
    char* da = smem + sl * 65536 + tt * 16;          // A panel: 256x64 = 32KB
    char* db = da + 32768;                           // B panel
    #pragma unroll
    for (int i = 0; i < 4; i++) {
      gl2lds16(pA + i * rstep + kt, da + i * 8192);
      gl2lds16(pB + i * rstep + kt, db + i * 8192);
    }
  };

  stage(0, 0);
  __syncthreads();

  for (int t = 0; t < T; t++) {
    const int s = t & 1;
    if (t + 1 < T) stage(t + 1, s ^ 1);   // lands during this tile's compute
    const char* as = smem + s * 65536;
    const char* bs = as + 32768;

    bf16x8 bfr[4][2];
    #pragma unroll
    for (int nf = 0; nf < 4; nf++) {
      bfr[nf][0] = *(const bf16x8*)(bs + bRow + nf * 2048 + tk0);
      bfr[nf][1] = *(const bf16x8*)(bs + bRow + nf * 2048 + tk1);
    }
    // m-half 0
    {
      bf16x8 af[4][2];
      #pragma unroll
      for (int mf = 0; mf < 4; mf++) {
        af[mf][0] = *(const bf16x8*)(as + aRow + mf * 2048 + tk0);
        af[mf][1] = *(const bf16x8*)(as + aRow + mf * 2048 + tk1);
      }
      #pragma unroll
      for (int mf = 0; mf < 4; mf++)
        #pragma unroll
        for (int nf = 0; nf < 4; nf++) {
          acc[mf][nf] = MFMA16(af[mf][0], bfr[nf][0], acc[mf][nf]);
          acc[mf][nf] = MFMA16(af[mf][1], bfr[nf][1], acc[mf][nf]);
        }
    }
    // m-half 1
    {
      bf16x8 af[4][2];
      #pragma unroll
      for (int mf = 0; mf < 4; mf++) {
        af[mf][0] = *(const bf16x8*)(as + aRow + (mf + 4) * 2048 + tk0);
        af[mf][1] = *(const bf16x8*)(as + aRow + (mf + 4) * 2048 + tk1);
      }
      #pragma unroll
      for (int mf = 0; mf < 4; mf++)
        #pragma unroll
        for (int nf = 0; nf < 4; nf++) {
          acc[mf + 4][nf] = MFMA16(af[mf][0], bfr[nf][0], acc[mf + 4][nf]);
          acc[mf + 4][nf] = MFMA16(af[mf][1], bfr[nf][1], acc[mf + 4][nf]);
        }
    }
    __syncthreads();   // single drain (vmcnt+lgkm) + barrier per K-tile
  }

  const int er = lq * 4;
  if (MODE == 0) {
    const int seg = n0 >> 11;
    const int gc = (n0 & 2047) + wn * 64 + l15;
    #pragma unroll
    for (int mf = 0; mf < 8; mf++)
      #pragma unroll
      for (int nf = 0; nf < 4; nf++) {
        const int gr = m0 + wm * 128 + mf * 16 + er;
        #pragma unroll
        for (int jj = 0; jj < 4; jj++) {
          const size_t off = (size_t)(gr + jj) * 2048 + gc + nf * 16;
          const float v = acc[mf][nf][jj];
          if (seg == 0) {
            oq[off] = (bf16_t)(1.0f / (1.0f + expf(-v)));
          } else if (seg == 1) {
            okk[off] = (bf16_t)(1.0f / (1.0f + expf(v)));
            og[off] = fminf(v, 0.0f) - log1pf(expf(-fabsf(v)));
          } else {
            ov[off] = (bf16_t)v;
          }
        }
      }
  } else {
    const int gc = n0 + wn * 64 + l15;
    #pragma unroll
    for (int mf = 0; mf < 8; mf++)
      #pragma unroll
      for (int nf = 0; nf < 4; nf++) {
        const int gr = m0 + wm * 128 + mf * 16 + er;
        #pragma unroll
        for (int jj = 0; jj < 4; jj++)
          of[(size_t)(gr + jj) * N + gc + nf * 16] = acc[mf][nf][jj];
      }
  }
}

// ---------------------------------------------------------------------------
__global__ void f2b_kernel(const float* __restrict__ in, bf16_t* __restrict__ out, int n8)
{
  const int idx = blockIdx.x * 256 + threadIdx.x;
  if (idx >= n8) return;
  const float4 a = *(const float4*)(in + (size_t)idx * 8);
  const float4 b = *(const float4*)(in + (size_t)idx * 8 + 4);
  bf16x8 o;
  o[0] = (bf16_t)a.x; o[1] = (bf16_t)a.y; o[2] = (bf16_t)a.z; o[3] = (bf16_t)a.w;
  o[4] = (bf16_t)b.x; o[5] = (bf16_t)b.y; o[6] = (bf16_t)b.z; o[7] = (bf16_t)b.w;
  *(bf16x8*)(out + (size_t)idx * 8) = o;
}

// ---------------------------------------------------------------------------
// prep2: per (b,h,c): gc = cumsum(g); IN-PLACE q <- q*e^(gc-gl/2),
// k <- k*e^(gl/2-gc); eglh[blk][d] = e^(gl_d/2).  (mid-point gauge)
// ---------------------------------------------------------------------------
__global__ __launch_bounds__(256)
void prep2_kernel(bf16_t* __restrict__ qb, bf16_t* __restrict__ kb,
                  const float* __restrict__ g32, float* __restrict__ eglh)
{
  __shared__ __align__(16) float gs[64][132];
  __shared__ float gls[128];
  const int blk = blockIdx.x;
  const int c = blk & 31, h = (blk >> 5) & 15, b = blk >> 9;
  const size_t row0 = (size_t)b * 2048 + (size_t)c * 64;
  const int col0 = h * 128;
  const int tt = threadIdx.x;

  #pragma unroll
  for (int s = 0; s < 8; s++) {
    const int u = tt + s * 256;
    const int t = u >> 5, d4 = (u & 31) * 4;
    *(float4*)&gs[t][d4] = *(const float4*)(g32 + (row0 + t) * 2048 + col0 + d4);
  }
  __syncthreads();
  if (tt < 128) {
    float run = 0.0f;
    for (int t = 0; t < 64; t++) { run += gs[t][tt]; gs[t][tt] = run; }
    gls[tt] = 0.5f * run;
    eglh[(size_t)blk * 128 + tt] = expf(0.5f * run);
  }
  __syncthreads();
  #pragma unroll
  for (int s = 0; s < 4; s++) {
    const int u = tt + s * 256;
    const int t = u >> 4, d8 = (u & 15) * 8;
    bf16_t* qp = qb + (row0 + t) * 2048 + col0 + d8;
    bf16_t* kp = kb + (row0 + t) * 2048 + col0 + d8;
    const bf16x8 q8 = *(const bf16x8*)qp;
    const bf16x8 k8 = *(const bf16x8*)kp;
    bf16x8 qo, ko2;
    #pragma unroll
    for (int j = 0; j < 8; j++) {
      const float gc = gs[t][d8 + j];
      const float gh = gls[d8 + j];
      qo[j]  = (bf16_t)((float)q8[j] * expf(gc - gh));
      ko2[j] = (bf16_t)((float)k8[j] * expf(gh - gc));
    }
    *(bf16x8*)qp = qo;
    *(bf16x8*)kp = ko2;
  }
}

// ---------------------------------------------------------------------------
// state2: per (bh, e-half, d-half): sequential 32-chunk recurrence on a
// 64x64 quarter of T = S^T. Stores pre-update state scaled by e^(gl_c/2).
// ---------------------------------------------------------------------------
__global__ __launch_bounds__(256)
void state2_kernel(const bf16_t* __restrict__ kb, const bf16_t* __restrict__ vb,
                   const float* __restrict__ eglh, bf16_t* __restrict__ ST)
{
  __shared__ __align__(16) bf16_t kgt[64][72];
  __shared__ __align__(16) bf16_t vt[64][72];
  __shared__ float ehs[64];
  const int blk = blockIdx.x;                   // bh*4 + eh*2 + dh
  const int dh = blk & 1, eh = (blk >> 1) & 1, bh = blk >> 2;
  const int b = bh >> 4, h = bh & 15;
  const int col0 = h * 128;
  const int tt = threadIdx.x, wave = tt >> 6, lane = tt & 63;
  const int r = lane & 15, ko = (lane >> 4) * 8;
  const int d0 = dh * 64, e0 = eh * 64;
  f32x4 acc[4] = {};

  for (int c = 0; c < 32; c++) {
    const size_t cb = (size_t)bh * 32 + c;
    const size_t row0 = (size_t)b * 2048 + (size_t)c * 64;
    if (tt < 64) ehs[tt] = eglh[cb * 128 + d0 + tt];
    __syncthreads();
    #pragma unroll
    for (int s = 0; s < 2; s++) {
      const int u = tt + s * 256;
      const int t = u >> 3, d8 = (u & 7) * 8;
      const bf16x8 kv = *(const bf16x8*)(kb + (row0 + t) * 2048 + col0 + d0 + d8);
      const bf16x8 vv = *(const bf16x8*)(vb + (row0 + t) * 2048 + col0 + e0 + d8);
      #pragma unroll
      for (int j = 0; j < 8; j++) {
        kgt[d8 + j][t] = (bf16_t)((float)kv[j] * ehs[d8 + j]);
        vt[d8 + j][t]  = vv[j];
      }
    }
    __syncthreads();
    #pragma unroll
    for (int nf = 0; nf < 4; nf++) {
      const int d = nf * 16 + r;
      const float sd = ehs[d];
      #pragma unroll
      for (int jj = 0; jj < 4; jj++) {
        const int e = e0 + wave * 16 + (lane >> 4) * 4 + jj;
        ST[(cb * 128 + e) * 128 + d0 + d] = (bf16_t)(acc[nf][jj] * sd);
      }
    }
    #pragma unroll
    for (int nf = 0; nf < 4; nf++) {
      const float ev = ehs[nf * 16 + r];
      const float e2 = ev * ev;
      #pragma unroll
      for (int jj = 0; jj < 4; jj++) acc[nf][jj] *= e2;
    }
    #pragma unroll
    for (int ks = 0; ks < 2; ks++) {
      const bf16x8 a = *(const bf16x8*)&vt[wave * 16 + r][ks * 32 + ko];
      #pragma unroll
      for (int nf = 0; nf < 4; nf++) {
        const bf16x8 bfr = *(const bf16x8*)&kgt[nf * 16 + r][ks * 32 + ko];
        acc[nf] = MFMA16(a, bfr, acc[nf]);
      }
    }
    __syncthreads();
  }
}

// ---------------------------------------------------------------------------
// chunk2: per (b,h,c): A = qg2 @ kd2^T (tril) -> P ; o = P@v + qg2@ST'
// ---------------------------------------------------------------------------
__global__ __launch_bounds__(256)
void chunk2_kernel(const bf16_t* __restrict__ qb, const bf16_t* __restrict__ kb,
                   const bf16_t* __restrict__ vb, const bf16_t* __restrict__ ST,
                   bf16_t* __restrict__ o16)
{
  __shared__ __align__(16) bf16_t qgs[64][136];
  __shared__ __align__(16) bf16_t kds[64][136];
  __shared__ __align__(16) bf16_t vTs[128][72];
  __shared__ __align__(16) bf16_t Ps[64][72];
  const int blk = blockIdx.x;
  const int c = blk & 31, h = (blk >> 5) & 15, b = blk >> 9;
  const size_t row0 = (size_t)b * 2048 + (size_t)c * 64;
  const int col0 = h * 128;
  const int tt = threadIdx.x, wave = tt >> 6, lane = tt & 63;
  const int r = lane & 15, ko = (lane >> 4) * 8;

  #pragma unroll
  for (int s = 0; s < 4; s++) {
    const int u = tt + s * 256;
    const int t = u >> 4, d8 = (u & 15) * 8;
    *(bf16x8*)&qgs[t][d8] = *(const bf16x8*)(qb + (row0 + t) * 2048 + col0 + d8);
    *(bf16x8*)&kds[t][d8] = *(const bf16x8*)(kb + (row0 + t) * 2048 + col0 + d8);
  }
  #pragma unroll
  for (int s = 0; s < 4; s++) {
    const int u = tt + s * 256;
    const int t = u >> 4, e8 = (u & 15) * 8;
    const bf16x8 vv = *(const bf16x8*)(vb + (row0 + t) * 2048 + col0 + e8);
    #pragma unroll
    for (int j = 0; j < 8; j++) vTs[e8 + j][t] = vv[j];
  }
  __syncthreads();

  bf16x8 aq[4];
  #pragma unroll
  for (int ks = 0; ks < 4; ks++) aq[ks] = *(const bf16x8*)&qgs[wave * 16 + r][ks * 32 + ko];

  f32x4 accA[4] = {};
  #pragma unroll
  for (int ks = 0; ks < 4; ks++)
    #pragma unroll
    for (int sf = 0; sf < 4; sf++) {
      const bf16x8 bfr = *(const bf16x8*)&kds[sf * 16 + r][ks * 32 + ko];
      accA[sf] = MFMA16(aq[ks], bfr, accA[sf]);
    }

  #pragma unroll
  for (int sf = 0; sf < 4; sf++)
    #pragma unroll
    for (int jj = 0; jj < 4; jj++) {
      const int t = wave * 16 + (lane >> 4) * 4 + jj;
      const int s = sf * 16 + r;
      Ps[t][s] = (bf16_t)(t >= s ? accA[sf][jj] : 0.0f);
    }

  f32x4 acc[8] = {};
  const size_t stbase = (size_t)blk * 128 * 128;
  #pragma unroll
  for (int ks = 0; ks < 4; ks++)
    #pragma unroll
    for (int ne = 0; ne < 8; ne++) {
      const bf16x8 bfr = *(const bf16x8*)(ST + stbase + (size_t)(ne * 16 + r) * 128 + ks * 32 + ko);
      acc[ne] = MFMA16(aq[ks], bfr, acc[ne]);
    }
  #pragma unroll
  for (int ks = 0; ks < 2; ks++) {
    const bf16x8 pa = *(const bf16x8*)&Ps[wave * 16 + r][ks * 32 + ko];
    #pragma unroll
    for (int ne = 0; ne < 8; ne++) {
      const bf16x8 bfr = *(const bf16x8*)&vTs[ne * 16 + r][ks * 32 + ko];
      acc[ne] = MFMA16(pa, bfr, acc[ne]);
    }
  }

  #pragma unroll
  for (int ne = 0; ne < 8; ne++)
    #pragma unroll
    for (int jj = 0; jj < 4; jj++) {
      const int t = wave * 16 + (lane >> 4) * 4 + jj;
      const int e = ne * 16 + r;
      o16[(row0 + t) * 2048 + col0 + e] = (bf16_t)acc[ne][jj];
    }
}

// ---------------------------------------------------------------------------
// RMSNorm over D=2048, bf16 in -> bf16 out
// ---------------------------------------------------------------------------
__global__ __launch_bounds__(256)
void rmsb_kernel(const bf16_t* __restrict__ o16, const float* __restrict__ w,
                 bf16_t* __restrict__ ob)
{
  __shared__ float red[4];
  const size_t row = blockIdx.x;
  const int tt = threadIdx.x;
  const bf16x8 v = *(const bf16x8*)(o16 + row * 2048 + tt * 8);
  float f[8], ss = 0.0f;
  #pragma unroll
  for (int j = 0; j < 8; j++) { f[j] = (float)v[j]; ss += f[j] * f[j]; }
  #pragma unroll
  for (int off = 32; off > 0; off >>= 1) ss += __shfl_down(ss, off);
  if ((tt & 63) == 0) red[tt >> 6] = ss;
  __syncthreads();
  const float inv = rsqrtf((red[0] + red[1] + red[2] + red[3]) * (1.0f / 2048.0f) + 1e-5f);
  const float4 w0 = *(const float4*)(w + tt * 8);
  const float4 w1 = *(const float4*)(w + tt * 8 + 4);
  bf16x8 o;
  o[0] = (bf16_t)(f[0] * inv * w0.x); o[1] = (bf16_t)(f[1] * inv * w0.y);
  o[2] = (bf16_t)(f[2] * inv * w0.z); o[3] = (bf16_t)(f[3] * inv * w0.w);
  o[4] = (bf16_t)(f[4] * inv * w1.x); o[5] = (bf16_t)(f[5] * inv * w1.y);
  o[6] = (bf16_t)(f[6] * inv * w1.z); o[7] = (bf16_t)(f[7] * inv * w1.w);
  *(bf16x8*)(ob + row * 2048 + tt * 8) = o;
}

// ---------------------------------------------------------------------------
extern "C" void kernel_launch(void* const* d_in, const int* in_sizes, int n_in,
                              void* d_out, int out_size, void* d_ws, size_t ws_size,
                              hipStream_t stream)
{
  const float* x  = (const float*)d_in[0];
  const float* Wq = (const float*)d_in[1];
  const float* Wf = (const float*)d_in[2];
  const float* Wi = (const float*)d_in[3];
  const float* Wo = (const float*)d_in[4];
  const float* gw = (const float*)d_in[5];
  float* out = (float*)d_out;
  char* ws = (char*)d_ws;

  const int K = 2048;
  const size_t MB = 1ull << 20;
  const int LDS = 131072;

  (void)hipFuncSetAttribute((const void*)gemm256<0>,
      hipFuncAttributeMaxDynamicSharedMemorySize, LDS);
  (void)hipFuncSetAttribute((const void*)gemm256<1>,
      hipFuncAttributeMaxDynamicSharedMemorySize, LDS);

  auto run = [&](const float* xs, float* outs, int nbs) {
    const int Ms = nbs * 2048;
    const size_t Sx = (size_t)Ms * 2048 * 2;     // bf16 matrix bytes
    bf16_t* xb  = (bf16_t*)(ws + 0);
    bf16_t* qb  = (bf16_t*)(ws + Sx);
    bf16_t* kb  = (bf16_t*)(ws + 2 * Sx);
    bf16_t* vb  = (bf16_t*)(ws + 3 * Sx);
    float*  g32 = (float*) (ws + 4 * Sx);        // 2*Sx bytes
    bf16_t* Wb  = (bf16_t*)(ws + 6 * Sx);        // 24 MiB (QKV fused / Wo)
    float*  egh = (float*) (ws + 6 * Sx + 24 * MB);
    bf16_t* STp = (bf16_t*)(ws + 4 * Sx);        // alias g32 (dead after prep)
    bf16_t* o16 = (bf16_t*)(ws + 0);             // alias xb  (dead after QKV gemm)
    bf16_t* ob  = (bf16_t*)(ws + Sx);            // alias qb  (dead after chunk)

    const int n8x = Ms * 2048 / 8;
    const int n8w = 2048 * 2048 / 8;

    f2b_kernel<<<(n8x + 255) / 256, 256, 0, stream>>>(xs, xb, n8x);
    f2b_kernel<<<(n8w + 255) / 256, 256, 0, stream>>>(Wq, Wb, n8w);
    f2b_kernel<<<(n8w + 255) / 256, 256, 0, stream>>>(Wf, Wb + 4194304, n8w);
    f2b_kernel<<<(n8w + 255) / 256, 256, 0, stream>>>(Wi, Wb + 8388608, n8w);

    gemm256<0><<<(Ms / 256) * (6144 / 256), 512, LDS, stream>>>(
        xb, Wb, qb, kb, vb, g32, nullptr, Ms, 6144, K);

    prep2_kernel<<<nbs * 512, 256, 0, stream>>>(qb, kb, g32, egh);
    state2_kernel<<<nbs * 64, 256, 0, stream>>>(kb, vb, egh, STp);
    chunk2_kernel<<<nbs * 512, 256, 0, stream>>>(qb, kb, vb, STp, o16);
    rmsb_kernel<<<Ms, 256, 0, stream>>>(o16, gw, ob);

    f2b_kernel<<<(n8w + 255) / 256, 256, 0, stream>>>(Wo, Wb, n8w);
    gemm256<1><<<(Ms / 256) * (2048 / 256), 512, LDS, stream>>>(
        ob, Wb, nullptr, nullptr, nullptr, nullptr, outs, Ms, 2048, K);
  };

  const size_t Sx_full = (size_t)8192 * 2048 * 2;
  const size_t need_full = 6 * Sx_full + 24 * MB + 2048 * 128 * 4;
  if (ws_size >= need_full) {
    run(x, out, 4);
  } else {
    for (int sb = 0; sb < 4; sb++)
      run(x + (size_t)sb * 2048 * 2048, out + (size_t)sb * 2048 * 2048, 1);
  }

  (void)in_sizes; (void)n_in; (void)out_size;
}

// Round 6
// 835.087 us; speedup vs baseline: 3.1673x; 3.1673x over previous
//
#include <hip/hip_runtime.h>
#include <math.h>

typedef __bf16 bf16_t;
typedef __bf16 bf16x8 __attribute__((ext_vector_type(8)));
typedef float  f32x4  __attribute__((ext_vector_type(4)));

__device__ __forceinline__ void gl2lds16(const void* g, void* l) {
  __builtin_amdgcn_global_load_lds((__attribute__((address_space(1))) void*)g,
                                   (__attribute__((address_space(3))) void*)l,
                                   16, 0, 0);
}

#define MFMA16(a, b, c) __builtin_amdgcn_mfma_f32_16x16x32_bf16(a, b, c, 0, 0, 0)

// ---------------------------------------------------------------------------
// 256x256 tile, BK=64, 8 waves (2M x 4N), 128 KiB LDS (2 buffers).
// Pipeline: stage(t+1) at iter top into buf s^1; 4 compute phases on buf s,
// each {4 ds_read_b128, 16 MFMA, plain s_barrier} (barrier segments live
// ranges -> acc stays in registers; R5's barrier-free body spilled acc to
// scratch, 6.6 GB/dispatch). NO asm lgkmcnt / sched_barrier / setprio pins
// (R4's pins = m141 failure mode). Single vmcnt(0)+s_barrier per K-tile.
// T2 swizzle byte ^= (row&7)<<4 on both sides (verified 0 conflicts).
// C = A * B^T. MODE 0: fused QKV epilogue (seg = n0>>11: 0->q=sigmoid,
// 1->k=sigmoid(-v) + g=logsigmoid(v), 2->v). MODE 1: f32 passthrough out.
// ---------------------------------------------------------------------------
template<int MODE>
__global__ __launch_bounds__(512, 1)
void gemm256(const bf16_t* __restrict__ A, const bf16_t* __restrict__ Bw,
             bf16_t* __restrict__ oq, bf16_t* __restrict__ okk,
             bf16_t* __restrict__ ov, float* __restrict__ og,
             float* __restrict__ of, int M, int N, int K)
{
  extern __shared__ __align__(16) char smem[];
  const int tt = threadIdx.x;
  const int wave = tt >> 6, lane = tt & 63;
  const int wm = wave >> 2, wn = wave & 3;
  const int nbn = N >> 8;
  const int m0 = (int)(blockIdx.x / nbn) << 8;
  const int n0 = (int)(blockIdx.x % nbn) << 8;
  const int l15 = lane & 15, lq = lane >> 4;

  // swizzled ds_read column terms (bytes): col ^ ((row&7)<<4); row&7 == lane&7
  const int tk0 = (lq * 16) ^ ((lane & 7) << 4);
  const int tk1 = (64 + lq * 16) ^ ((lane & 7) << 4);
  const int aRow = (wm * 128 + l15) * 128;   // byte base of lane's A row
  const int bRow = (wn * 64  + l15) * 128;   // byte base of lane's B row

  // staging: thread t writes LDS bytes tt*16 + i*8192 of a 32KB panel
  // -> row = (tt>>3)+i*64, slot = tt&7.  Pre-swizzled global source col.
  const int srow = tt >> 3;
  const int scol = ((tt & 7) * 8) ^ ((srow & 7) * 8);      // elements
  const bf16_t* pA = A  + (size_t)(m0 + srow) * K + scol;
  const bf16_t* pB = Bw + (size_t)(n0 + srow) * K + scol;
  const size_t rstep = (size_t)64 * K;

  f32x4 acc[8][4] = {};
  const int T = K >> 6;

  auto stage = [&](int t, int sl) {
    const int kt = t << 6;
    char* da = smem + sl * 65536 + wave * 1024;      // A panel: 256x64 = 32KB
    char* db = da + 32768;                           // B panel
    #pragma unroll
    for (int i = 0; i < 4; i++) {
      gl2lds16(pA + i * rstep + kt, da + i * 8192);
      gl2lds16(pB + i * rstep + kt, db + i * 8192);
    }
  };

  stage(0, 0);
  asm volatile("s_waitcnt vmcnt(0)" ::: "memory");
  __builtin_amdgcn_s_barrier();

  for (int t = 0; t < T; t++) {
    const int s = t & 1;
    if (t + 1 < T) stage(t + 1, s ^ 1);   // lands during this tile's compute
    const char* as = smem + s * 65536;
    const char* bs = as + 32768;

    bf16x8 bfr[4][2];
    #pragma unroll
    for (int nf = 0; nf < 4; nf++) {
      bfr[nf][0] = *(const bf16x8*)(bs + bRow + nf * 2048 + tk0);
      bfr[nf][1] = *(const bf16x8*)(bs + bRow + nf * 2048 + tk1);
    }
    #pragma unroll
    for (int p = 0; p < 4; p++) {
      bf16x8 af[2][2];
      #pragma unroll
      for (int mm = 0; mm < 2; mm++) {
        af[mm][0] = *(const bf16x8*)(as + aRow + (p * 2 + mm) * 2048 + tk0);
        af[mm][1] = *(const bf16x8*)(as + aRow + (p * 2 + mm) * 2048 + tk1);
      }
      #pragma unroll
      for (int mm = 0; mm < 2; mm++)
        #pragma unroll
        for (int nf = 0; nf < 4; nf++) {
          acc[p * 2 + mm][nf] = MFMA16(af[mm][0], bfr[nf][0], acc[p * 2 + mm][nf]);
          acc[p * 2 + mm][nf] = MFMA16(af[mm][1], bfr[nf][1], acc[p * 2 + mm][nf]);
        }
      // phase fence: keeps ds_reads of later phases from hoisting (live-range
      // segmentation -> acc stays in AGPR/VGPR, no scratch spill)
      __builtin_amdgcn_s_barrier();
    }
    asm volatile("s_waitcnt vmcnt(0)" ::: "memory");  // tile t+1 landed long ago
    __builtin_amdgcn_s_barrier();
  }

  const int er = lq * 4;
  if (MODE == 0) {
    const int seg = n0 >> 11;
    const int gc = (n0 & 2047) + wn * 64 + l15;
    #pragma unroll
    for (int mf = 0; mf < 8; mf++)
      #pragma unroll
      for (int nf = 0; nf < 4; nf++) {
        const int gr = m0 + wm * 128 + mf * 16 + er;
        #pragma unroll
        for (int jj = 0; jj < 4; jj++) {
          const size_t off = (size_t)(gr + jj) * 2048 + gc + nf * 16;
          const float v = acc[mf][nf][jj];
          if (seg == 0) {
            oq[off] = (bf16_t)(1.0f / (1.0f + expf(-v)));
          } else if (seg == 1) {
            okk[off] = (bf16_t)(1.0f / (1.0f + expf(v)));
            og[off] = fminf(v, 0.0f) - log1pf(expf(-fabsf(v)));
          } else {
            ov[off] = (bf16_t)v;
          }
        }
      }
  } else {
    const int gc = n0 + wn * 64 + l15;
    #pragma unroll
    for (int mf = 0; mf < 8; mf++)
      #pragma unroll
      for (int nf = 0; nf < 4; nf++) {
        const int gr = m0 + wm * 128 + mf * 16 + er;
        #pragma unroll
        for (int jj = 0; jj < 4; jj++)
          of[(size_t)(gr + jj) * N + gc + nf * 16] = acc[mf][nf][jj];
      }
  }
}

// ---------------------------------------------------------------------------
__global__ void f2b_kernel(const float* __restrict__ in, bf16_t* __restrict__ out, int n8)
{
  const int idx = blockIdx.x * 256 + threadIdx.x;
  if (idx >= n8) return;
  const float4 a = *(const float4*)(in + (size_t)idx * 8);
  const float4 b = *(const float4*)(in + (size_t)idx * 8 + 4);
  bf16x8 o;
  o[0] = (bf16_t)a.x; o[1] = (bf16_t)a.y; o[2] = (bf16_t)a.z; o[3] = (bf16_t)a.w;
  o[4] = (bf16_t)b.x; o[5] = (bf16_t)b.y; o[6] = (bf16_t)b.z; o[7] = (bf16_t)b.w;
  *(bf16x8*)(out + (size_t)idx * 8) = o;
}

// ---------------------------------------------------------------------------
// prep2: per (b,h,c): gc = cumsum(g); IN-PLACE q <- q*e^(gc-gl/2),
// k <- k*e^(gl/2-gc); eglh[blk][d] = e^(gl_d/2).  (mid-point gauge)
// ---------------------------------------------------------------------------
__global__ __launch_bounds__(256)
void prep2_kernel(bf16_t* __restrict__ qb, bf16_t* __restrict__ kb,
                  const float* __restrict__ g32, float* __restrict__ eglh)
{
  __shared__ __align__(16) float gs[64][132];
  __shared__ float gls[128];
  const int blk = blockIdx.x;
  const int c = blk & 31, h = (blk >> 5) & 15, b = blk >> 9;
  const size_t row0 = (size_t)b * 2048 + (size_t)c * 64;
  const int col0 = h * 128;
  const int tt = threadIdx.x;

  #pragma unroll
  for (int s = 0; s < 8; s++) {
    const int u = tt + s * 256;
    const int t = u >> 5, d4 = (u & 31) * 4;
    *(float4*)&gs[t][d4] = *(const float4*)(g32 + (row0 + t) * 2048 + col0 + d4);
  }
  __syncthreads();
  if (tt < 128) {
    float run = 0.0f;
    for (int t = 0; t < 64; t++) { run += gs[t][tt]; gs[t][tt] = run; }
    gls[tt] = 0.5f * run;
    eglh[(size_t)blk * 128 + tt] = expf(0.5f * run);
  }
  __syncthreads();
  #pragma unroll
  for (int s = 0; s < 4; s++) {
    const int u = tt + s * 256;
    const int t = u >> 4, d8 = (u & 15) * 8;
    bf16_t* qp = qb + (row0 + t) * 2048 + col0 + d8;
    bf16_t* kp = kb + (row0 + t) * 2048 + col0 + d8;
    const bf16x8 q8 = *(const bf16x8*)qp;
    const bf16x8 k8 = *(const bf16x8*)kp;
    bf16x8 qo, ko2;
    #pragma unroll
    for (int j = 0; j < 8; j++) {
      const float gc = gs[t][d8 + j];
      const float gh = gls[d8 + j];
      qo[j]  = (bf16_t)((float)q8[j] * expf(gc - gh));
      ko2[j] = (bf16_t)((float)k8[j] * expf(gh - gc));
    }
    *(bf16x8*)qp = qo;
    *(bf16x8*)kp = ko2;
  }
}

// ---------------------------------------------------------------------------
// state2: per (bh, e-half, d-half): sequential 32-chunk recurrence on a
// 64x64 quarter of T = S^T. Stores pre-update state scaled by e^(gl_c/2).
// ---------------------------------------------------------------------------
__global__ __launch_bounds__(256)
void state2_kernel(const bf16_t* __restrict__ kb, const bf16_t* __restrict__ vb,
                   const float* __restrict__ eglh, bf16_t* __restrict__ ST)
{
  __shared__ __align__(16) bf16_t kgt[64][72];
  __shared__ __align__(16) bf16_t vt[64][72];
  __shared__ float ehs[64];
  const int blk = blockIdx.x;                   // bh*4 + eh*2 + dh
  const int dh = blk & 1, eh = (blk >> 1) & 1, bh = blk >> 2;
  const int b = bh >> 4, h = bh & 15;
  const int col0 = h * 128;
  const int tt = threadIdx.x, wave = tt >> 6, lane = tt & 63;
  const int r = lane & 15, ko = (lane >> 4) * 8;
  const int d0 = dh * 64, e0 = eh * 64;
  f32x4 acc[4] = {};

  for (int c = 0; c < 32; c++) {
    const size_t cb = (size_t)bh * 32 + c;
    const size_t row0 = (size_t)b * 2048 + (size_t)c * 64;
    if (tt < 64) ehs[tt] = eglh[cb * 128 + d0 + tt];
    __syncthreads();
    #pragma unroll
    for (int s = 0; s < 2; s++) {
      const int u = tt + s * 256;
      const int t = u >> 3, d8 = (u & 7) * 8;
      const bf16x8 kv = *(const bf16x8*)(kb + (row0 + t) * 2048 + col0 + d0 + d8);
      const bf16x8 vv = *(const bf16x8*)(vb + (row0 + t) * 2048 + col0 + e0 + d8);
      #pragma unroll
      for (int j = 0; j < 8; j++) {
        kgt[d8 + j][t] = (bf16_t)((float)kv[j] * ehs[d8 + j]);
        vt[d8 + j][t]  = vv[j];
      }
    }
    __syncthreads();
    #pragma unroll
    for (int nf = 0; nf < 4; nf++) {
      const int d = nf * 16 + r;
      const float sd = ehs[d];
      #pragma unroll
      for (int jj = 0; jj < 4; jj++) {
        const int e = e0 + wave * 16 + (lane >> 4) * 4 + jj;
        ST[(cb * 128 + e) * 128 + d0 + d] = (bf16_t)(acc[nf][jj] * sd);
      }
    }
    #pragma unroll
    for (int nf = 0; nf < 4; nf++) {
      const float ev = ehs[nf * 16 + r];
      const float e2 = ev * ev;
      #pragma unroll
      for (int jj = 0; jj < 4; jj++) acc[nf][jj] *= e2;
    }
    #pragma unroll
    for (int ks = 0; ks < 2; ks++) {
      const bf16x8 a = *(const bf16x8*)&vt[wave * 16 + r][ks * 32 + ko];
      #pragma unroll
      for (int nf = 0; nf < 4; nf++) {
        const bf16x8 bfr = *(const bf16x8*)&kgt[nf * 16 + r][ks * 32 + ko];
        acc[nf] = MFMA16(a, bfr, acc[nf]);
      }
    }
    __syncthreads();
  }
}

// ---------------------------------------------------------------------------
// chunk2: per (b,h,c): A = qg2 @ kd2^T (tril) -> P ; o = P@v + qg2@ST'
// ---------------------------------------------------------------------------
__global__ __launch_bounds__(256)
void chunk2_kernel(const bf16_t* __restrict__ qb, const bf16_t* __restrict__ kb,
                   const bf16_t* __restrict__ vb, const bf16_t* __restrict__ ST,
                   bf16_t* __restrict__ o16)
{
  __shared__ __align__(16) bf16_t qgs[64][136];
  __shared__ __align__(16) bf16_t kds[64][136];
  __shared__ __align__(16) bf16_t vTs[128][72];
  __shared__ __align__(16) bf16_t Ps[64][72];
  const int blk = blockIdx.x;
  const int c = blk & 31, h = (blk >> 5) & 15, b = blk >> 9;
  const size_t row0 = (size_t)b * 2048 + (size_t)c * 64;
  const int col0 = h * 128;
  const int tt = threadIdx.x, wave = tt >> 6, lane = tt & 63;
  const int r = lane & 15, ko = (lane >> 4) * 8;

  #pragma unroll
  for (int s = 0; s < 4; s++) {
    const int u = tt + s * 256;
    const int t = u >> 4, d8 = (u & 15) * 8;
    *(bf16x8*)&qgs[t][d8] = *(const bf16x8*)(qb + (row0 + t) * 2048 + col0 + d8);
    *(bf16x8*)&kds[t][d8] = *(const bf16x8*)(kb + (row0 + t) * 2048 + col0 + d8);
  }
  #pragma unroll
  for (int s = 0; s < 4; s++) {
    const int u = tt + s * 256;
    const int t = u >> 4, e8 = (u & 15) * 8;
    const bf16x8 vv = *(const bf16x8*)(vb + (row0 + t) * 2048 + col0 + e8);
    #pragma unroll
    for (int j = 0; j < 8; j++) vTs[e8 + j][t] = vv[j];
  }
  __syncthreads();

  bf16x8 aq[4];
  #pragma unroll
  for (int ks = 0; ks < 4; ks++) aq[ks] = *(const bf16x8*)&qgs[wave * 16 + r][ks * 32 + ko];

  f32x4 accA[4] = {};
  #pragma unroll
  for (int ks = 0; ks < 4; ks++)
    #pragma unroll
    for (int sf = 0; sf < 4; sf++) {
      const bf16x8 bfr = *(const bf16x8*)&kds[sf * 16 + r][ks * 32 + ko];
      accA[sf] = MFMA16(aq[ks], bfr, accA[sf]);
    }

  #pragma unroll
  for (int sf = 0; sf < 4; sf++)
    #pragma unroll
    for (int jj = 0; jj < 4; jj++) {
      const int t = wave * 16 + (lane >> 4) * 4 + jj;
      const int s = sf * 16 + r;
      Ps[t][s] = (bf16_t)(t >= s ? accA[sf][jj] : 0.0f);
    }

  f32x4 acc[8] = {};
  const size_t stbase = (size_t)blk * 128 * 128;
  #pragma unroll
  for (int ks = 0; ks < 4; ks++)
    #pragma unroll
    for (int ne = 0; ne < 8; ne++) {
      const bf16x8 bfr = *(const bf16x8*)(ST + stbase + (size_t)(ne * 16 + r) * 128 + ks * 32 + ko);
      acc[ne] = MFMA16(aq[ks], bfr, acc[ne]);
    }
  #pragma unroll
  for (int ks = 0; ks < 2; ks++) {
    const bf16x8 pa = *(const bf16x8*)&Ps[wave * 16 + r][ks * 32 + ko];
    #pragma unroll
    for (int ne = 0; ne < 8; ne++) {
      const bf16x8 bfr = *(const bf16x8*)&vTs[ne * 16 + r][ks * 32 + ko];
      acc[ne] = MFMA16(pa, bfr, acc[ne]);
    }
  }

  #pragma unroll
  for (int ne = 0; ne < 8; ne++)
    #pragma unroll
    for (int jj = 0; jj < 4; jj++) {
      const int t = wave * 16 + (lane >> 4) * 4 + jj;
      const int e = ne * 16 + r;
      o16[(row0 + t) * 2048 + col0 + e] = (bf16_t)acc[ne][jj];
    }
}

// ---------------------------------------------------------------------------
// RMSNorm over D=2048, bf16 in -> bf16 out
// ---------------------------------------------------------------------------
__global__ __launch_bounds__(256)
void rmsb_kernel(const bf16_t* __restrict__ o16, const float* __restrict__ w,
                 bf16_t* __restrict__ ob)
{
  __shared__ float red[4];
  const size_t row = blockIdx.x;
  const int tt = threadIdx.x;
  const bf16x8 v = *(const bf16x8*)(o16 + row * 2048 + tt * 8);
  float f[8], ss = 0.0f;
  #pragma unroll
  for (int j = 0; j < 8; j++) { f[j] = (float)v[j]; ss += f[j] * f[j]; }
  #pragma unroll
  for (int off = 32; off > 0; off >>= 1) ss += __shfl_down(ss, off);
  if ((tt & 63) == 0) red[tt >> 6] = ss;
  __syncthreads();
  const float inv = rsqrtf((red[0] + red[1] + red[2] + red[3]) * (1.0f / 2048.0f) + 1e-5f);
  const float4 w0 = *(const float4*)(w + tt * 8);
  const float4 w1 = *(const float4*)(w + tt * 8 + 4);
  bf16x8 o;
  o[0] = (bf16_t)(f[0] * inv * w0.x); o[1] = (bf16_t)(f[1] * inv * w0.y);
  o[2] = (bf16_t)(f[2] * inv * w0.z); o[3] = (bf16_t)(f[3] * inv * w0.w);
  o[4] = (bf16_t)(f[4] * inv * w1.x); o[5] = (bf16_t)(f[5] * inv * w1.y);
  o[6] = (bf16_t)(f[6] * inv * w1.z); o[7] = (bf16_t)(f[7] * inv * w1.w);
  *(bf16x8*)(ob + row * 2048 + tt * 8) = o;
}

// ---------------------------------------------------------------------------
extern "C" void kernel_launch(void* const* d_in, const int* in_sizes, int n_in,
                              void* d_out, int out_size, void* d_ws, size_t ws_size,
                              hipStream_t stream)
{
  const float* x  = (const float*)d_in[0];
  const float* Wq = (const float*)d_in[1];
  const float* Wf = (const float*)d_in[2];
  const float* Wi = (const float*)d_in[3];
  const float* Wo = (const float*)d_in[4];
  const float* gw = (const float*)d_in[5];
  float* out = (float*)d_out;
  char* ws = (char*)d_ws;

  const int K = 2048;
  const size_t MB = 1ull << 20;
  const int LDS = 131072;

  (void)hipFuncSetAttribute((const void*)gemm256<0>,
      hipFuncAttributeMaxDynamicSharedMemorySize, LDS);
  (void)hipFuncSetAttribute((const void*)gemm256<1>,
      hipFuncAttributeMaxDynamicSharedMemorySize, LDS);

  auto run = [&](const float* xs, float* outs, int nbs) {
    const int Ms = nbs * 2048;
    const size_t Sx = (size_t)Ms * 2048 * 2;     // bf16 matrix bytes
    bf16_t* xb  = (bf16_t*)(ws + 0);
    bf16_t* qb  = (bf16_t*)(ws + Sx);
    bf16_t* kb  = (bf16_t*)(ws + 2 * Sx);
    bf16_t* vb  = (bf16_t*)(ws + 3 * Sx);
    float*  g32 = (float*) (ws + 4 * Sx);        // 2*Sx bytes
    bf16_t* Wb  = (bf16_t*)(ws + 6 * Sx);        // 24 MiB (QKV fused / Wo)
    float*  egh = (float*) (ws + 6 * Sx + 24 * MB);
    bf16_t* STp = (bf16_t*)(ws + 4 * Sx);        // alias g32 (dead after prep)
    bf16_t* o16 = (bf16_t*)(ws + 0);             // alias xb  (dead after QKV gemm)
    bf16_t* ob  = (bf16_t*)(ws + Sx);            // alias qb  (dead after chunk)

    const int n8x = Ms * 2048 / 8;
    const int n8w = 2048 * 2048 / 8;

    f2b_kernel<<<(n8x + 255) / 256, 256, 0, stream>>>(xs, xb, n8x);
    f2b_kernel<<<(n8w + 255) / 256, 256, 0, stream>>>(Wq, Wb, n8w);
    f2b_kernel<<<(n8w + 255) / 256, 256, 0, stream>>>(Wf, Wb + 4194304, n8w);
    f2b_kernel<<<(n8w + 255) / 256, 256, 0, stream>>>(Wi, Wb + 8388608, n8w);

    gemm256<0><<<(Ms / 256) * (6144 / 256), 512, LDS, stream>>>(
        xb, Wb, qb, kb, vb, g32, nullptr, Ms, 6144, K);

    prep2_kernel<<<nbs * 512, 256, 0, stream>>>(qb, kb, g32, egh);
    state2_kernel<<<nbs * 64, 256, 0, stream>>>(kb, vb, egh, STp);
    chunk2_kernel<<<nbs * 512, 256, 0, stream>>>(qb, kb, vb, STp, o16);
    rmsb_kernel<<<Ms, 256, 0, stream>>>(o16, gw, ob);

    f2b_kernel<<<(n8w + 255) / 256, 256, 0, stream>>>(Wo, Wb, n8w);
    gemm256<1><<<(Ms / 256) * (2048 / 256), 512, LDS, stream>>>(
        ob, Wb, nullptr, nullptr, nullptr, nullptr, outs, Ms, 2048, K);
  };

  const size_t Sx_full = (size_t)8192 * 2048 * 2;
  const size_t need_full = 6 * Sx_full + 24 * MB + 2048 * 128 * 4;
  if (ws_size >= need_full) {
    run(x, out, 4);
  } else {
    for (int sb = 0; sb < 4; sb++)
      run(x + (size_t)sb * 2048 * 2048, out + (size_t)sb * 2048 * 2048, 1);
  }

  (void)in_sizes; (void)n_in; (void)out_size;
}

// Round 7
// 830.270 us; speedup vs baseline: 3.1857x; 1.0058x over previous
//
#include <hip/hip_runtime.h>
#include <math.h>

typedef __bf16 bf16_t;
typedef __bf16 bf16x8 __attribute__((ext_vector_type(8)));
typedef float  f32x4  __attribute__((ext_vector_type(4)));

__device__ __forceinline__ void gl2lds16(const void* g, void* l) {
  __builtin_amdgcn_global_load_lds((__attribute__((address_space(1))) void*)g,
                                   (__attribute__((address_space(3))) void*)l,
                                   16, 0, 0);
}

#define MFMA16(a, b, c) __builtin_amdgcn_mfma_f32_16x16x32_bf16(a, b, c, 0, 0, 0)

// ---------------------------------------------------------------------------
// 256x256 tile, BK=64, 8 waves (2M x 4N), 128 KiB LDS (2 buffers).
// K-loop: stage(t+1) at top (8 global_load_lds); 8 B-frag ds_reads; then
// 4 phases of {4 A-frag ds_reads, sched_barrier(0), 16 MFMA, sched_barrier(0)}
// -- sched_barrier is COMPILE-TIME only: segments live ranges (R5 without
// fences spilled acc -> 6.6 GB scratch traffic) at zero runtime cost (R4/R6
// runtime s_barriers per phase serialized the block -> 14.5% MfmaUtil).
// ONE vmcnt(0) + s_barrier per K-tile (double-buffer WAR: buf s rewritten at
// t+2, one barrier between -> race-free).
// T2 swizzle byte ^= (row&7)<<4 on both sides (verified 0 conflicts).
// C = A * B^T. MODE 0: fused QKV epilogue (seg = n0>>11: 0->q=sigmoid,
// 1->k=sigmoid(-v) + g=logsigmoid(v), 2->v). MODE 1: f32 passthrough out.
// ---------------------------------------------------------------------------
template<int MODE>
__global__ __launch_bounds__(512, 1)
void gemm256(const bf16_t* __restrict__ A, const bf16_t* __restrict__ Bw,
             bf16_t* __restrict__ oq, bf16_t* __restrict__ okk,
             bf16_t* __restrict__ ov, float* __restrict__ og,
             float* __restrict__ of, int M, int N, int K)
{
  extern __shared__ __align__(16) char smem[];
  const int tt = threadIdx.x;
  const int wave = tt >> 6, lane = tt & 63;
  const int wm = wave >> 2, wn = wave & 3;
  const int nbn = N >> 8;
  const int m0 = (int)(blockIdx.x / nbn) << 8;
  const int n0 = (int)(blockIdx.x % nbn) << 8;
  const int l15 = lane & 15, lq = lane >> 4;

  // swizzled ds_read column terms (bytes): col ^ ((row&7)<<4); row&7 == lane&7
  const int tk0 = (lq * 16) ^ ((lane & 7) << 4);
  const int tk1 = (64 + lq * 16) ^ ((lane & 7) << 4);
  const int aRow = (wm * 128 + l15) * 128;   // byte base of lane's A row
  const int bRow = (wn * 64  + l15) * 128;   // byte base of lane's B row

  // staging: thread t writes LDS bytes tt*16 + i*8192 of a 32KB panel
  // -> row = (tt>>3)+i*64, slot = tt&7.  Pre-swizzled global source col.
  const int srow = tt >> 3;
  const int scol = ((tt & 7) * 8) ^ ((srow & 7) * 8);      // elements
  const bf16_t* pA = A  + (size_t)(m0 + srow) * K + scol;
  const bf16_t* pB = Bw + (size_t)(n0 + srow) * K + scol;
  const size_t rstep = (size_t)64 * K;

  f32x4 acc[8][4] = {};
  const int T = K >> 6;

  auto stage = [&](int t, int sl) {
    const int kt = t << 6;
    char* da = smem + sl * 65536 + wave * 1024;      // A panel: 256x64 = 32KB
    char* db = da + 32768;                           // B panel
    #pragma unroll
    for (int i = 0; i < 4; i++) {
      gl2lds16(pA + i * rstep + kt, da + i * 8192);
      gl2lds16(pB + i * rstep + kt, db + i * 8192);
    }
  };

  stage(0, 0);
  asm volatile("s_waitcnt vmcnt(0)" ::: "memory");
  __builtin_amdgcn_s_barrier();

  for (int t = 0; t < T; t++) {
    const int s = t & 1;
    if (t + 1 < T) stage(t + 1, s ^ 1);   // lands during this tile's compute
    const char* as = smem + s * 65536;
    const char* bs = as + 32768;

    bf16x8 bfr[4][2];
    #pragma unroll
    for (int nf = 0; nf < 4; nf++) {
      bfr[nf][0] = *(const bf16x8*)(bs + bRow + nf * 2048 + tk0);
      bfr[nf][1] = *(const bf16x8*)(bs + bRow + nf * 2048 + tk1);
    }
    #pragma unroll
    for (int p = 0; p < 4; p++) {
      bf16x8 af[2][2];
      #pragma unroll
      for (int mm = 0; mm < 2; mm++) {
        af[mm][0] = *(const bf16x8*)(as + aRow + (p * 2 + mm) * 2048 + tk0);
        af[mm][1] = *(const bf16x8*)(as + aRow + (p * 2 + mm) * 2048 + tk1);
      }
      // compile-time fence only: bounds the scheduler's window so acc stays
      // in registers (R5 spill) WITHOUT serializing waves (R4/R6 barriers)
      __builtin_amdgcn_sched_barrier(0);
      #pragma unroll
      for (int mm = 0; mm < 2; mm++)
        #pragma unroll
        for (int nf = 0; nf < 4; nf++) {
          acc[p * 2 + mm][nf] = MFMA16(af[mm][0], bfr[nf][0], acc[p * 2 + mm][nf]);
          acc[p * 2 + mm][nf] = MFMA16(af[mm][1], bfr[nf][1], acc[p * 2 + mm][nf]);
        }
      __builtin_amdgcn_sched_barrier(0);
    }
    asm volatile("s_waitcnt vmcnt(0)" ::: "memory");  // tile t+1 landed under compute
    __builtin_amdgcn_s_barrier();                     // single runtime sync per tile
  }

  const int er = lq * 4;
  if (MODE == 0) {
    const int seg = n0 >> 11;
    const int gc = (n0 & 2047) + wn * 64 + l15;
    #pragma unroll
    for (int mf = 0; mf < 8; mf++)
      #pragma unroll
      for (int nf = 0; nf < 4; nf++) {
        const int gr = m0 + wm * 128 + mf * 16 + er;
        #pragma unroll
        for (int jj = 0; jj < 4; jj++) {
          const size_t off = (size_t)(gr + jj) * 2048 + gc + nf * 16;
          const float v = acc[mf][nf][jj];
          if (seg == 0) {
            oq[off] = (bf16_t)(1.0f / (1.0f + expf(-v)));
          } else if (seg == 1) {
            okk[off] = (bf16_t)(1.0f / (1.0f + expf(v)));
            og[off] = fminf(v, 0.0f) - log1pf(expf(-fabsf(v)));
          } else {
            ov[off] = (bf16_t)v;
          }
        }
      }
  } else {
    const int gc = n0 + wn * 64 + l15;
    #pragma unroll
    for (int mf = 0; mf < 8; mf++)
      #pragma unroll
      for (int nf = 0; nf < 4; nf++) {
        const int gr = m0 + wm * 128 + mf * 16 + er;
        #pragma unroll
        for (int jj = 0; jj < 4; jj++)
          of[(size_t)(gr + jj) * N + gc + nf * 16] = acc[mf][nf][jj];
      }
  }
}

// ---------------------------------------------------------------------------
__global__ void f2b_kernel(const float* __restrict__ in, bf16_t* __restrict__ out, int n8)
{
  const int idx = blockIdx.x * 256 + threadIdx.x;
  if (idx >= n8) return;
  const float4 a = *(const float4*)(in + (size_t)idx * 8);
  const float4 b = *(const float4*)(in + (size_t)idx * 8 + 4);
  bf16x8 o;
  o[0] = (bf16_t)a.x; o[1] = (bf16_t)a.y; o[2] = (bf16_t)a.z; o[3] = (bf16_t)a.w;
  o[4] = (bf16_t)b.x; o[5] = (bf16_t)b.y; o[6] = (bf16_t)b.z; o[7] = (bf16_t)b.w;
  *(bf16x8*)(out + (size_t)idx * 8) = o;
}

// ---------------------------------------------------------------------------
// prep2: per (b,h,c): gc = cumsum(g); IN-PLACE q <- q*e^(gc-gl/2),
// k <- k*e^(gl/2-gc); eglh[blk][d] = e^(gl_d/2).  (mid-point gauge)
// ---------------------------------------------------------------------------
__global__ __launch_bounds__(256)
void prep2_kernel(bf16_t* __restrict__ qb, bf16_t* __restrict__ kb,
                  const float* __restrict__ g32, float* __restrict__ eglh)
{
  __shared__ __align__(16) float gs[64][132];
  __shared__ float gls[128];
  const int blk = blockIdx.x;
  const int c = blk & 31, h = (blk >> 5) & 15, b = blk >> 9;
  const size_t row0 = (size_t)b * 2048 + (size_t)c * 64;
  const int col0 = h * 128;
  const int tt = threadIdx.x;

  #pragma unroll
  for (int s = 0; s < 8; s++) {
    const int u = tt + s * 256;
    const int t = u >> 5, d4 = (u & 31) * 4;
    *(float4*)&gs[t][d4] = *(const float4*)(g32 + (row0 + t) * 2048 + col0 + d4);
  }
  __syncthreads();
  if (tt < 128) {
    float run = 0.0f;
    for (int t = 0; t < 64; t++) { run += gs[t][tt]; gs[t][tt] = run; }
    gls[tt] = 0.5f * run;
    eglh[(size_t)blk * 128 + tt] = expf(0.5f * run);
  }
  __syncthreads();
  #pragma unroll
  for (int s = 0; s < 4; s++) {
    const int u = tt + s * 256;
    const int t = u >> 4, d8 = (u & 15) * 8;
    bf16_t* qp = qb + (row0 + t) * 2048 + col0 + d8;
    bf16_t* kp = kb + (row0 + t) * 2048 + col0 + d8;
    const bf16x8 q8 = *(const bf16x8*)qp;
    const bf16x8 k8 = *(const bf16x8*)kp;
    bf16x8 qo, ko2;
    #pragma unroll
    for (int j = 0; j < 8; j++) {
      const float gc = gs[t][d8 + j];
      const float gh = gls[d8 + j];
      qo[j]  = (bf16_t)((float)q8[j] * expf(gc - gh));
      ko2[j] = (bf16_t)((float)k8[j] * expf(gh - gc));
    }
    *(bf16x8*)qp = qo;
    *(bf16x8*)kp = ko2;
  }
}

// ---------------------------------------------------------------------------
// state2: per (bh, e-half, d-half): sequential 32-chunk recurrence on a
// 64x64 quarter of T = S^T. Stores pre-update state scaled by e^(gl_c/2).
// ---------------------------------------------------------------------------
__global__ __launch_bounds__(256)
void state2_kernel(const bf16_t* __restrict__ kb, const bf16_t* __restrict__ vb,
                   const float* __restrict__ eglh, bf16_t* __restrict__ ST)
{
  __shared__ __align__(16) bf16_t kgt[64][72];
  __shared__ __align__(16) bf16_t vt[64][72];
  __shared__ float ehs[64];
  const int blk = blockIdx.x;                   // bh*4 + eh*2 + dh
  const int dh = blk & 1, eh = (blk >> 1) & 1, bh = blk >> 2;
  const int b = bh >> 4, h = bh & 15;
  const int col0 = h * 128;
  const int tt = threadIdx.x, wave = tt >> 6, lane = tt & 63;
  const int r = lane & 15, ko = (lane >> 4) * 8;
  const int d0 = dh * 64, e0 = eh * 64;
  f32x4 acc[4] = {};

  for (int c = 0; c < 32; c++) {
    const size_t cb = (size_t)bh * 32 + c;
    const size_t row0 = (size_t)b * 2048 + (size_t)c * 64;
    if (tt < 64) ehs[tt] = eglh[cb * 128 + d0 + tt];
    __syncthreads();
    #pragma unroll
    for (int s = 0; s < 2; s++) {
      const int u = tt + s * 256;
      const int t = u >> 3, d8 = (u & 7) * 8;
      const bf16x8 kv = *(const bf16x8*)(kb + (row0 + t) * 2048 + col0 + d0 + d8);
      const bf16x8 vv = *(const bf16x8*)(vb + (row0 + t) * 2048 + col0 + e0 + d8);
      #pragma unroll
      for (int j = 0; j < 8; j++) {
        kgt[d8 + j][t] = (bf16_t)((float)kv[j] * ehs[d8 + j]);
        vt[d8 + j][t]  = vv[j];
      }
    }
    __syncthreads();
    #pragma unroll
    for (int nf = 0; nf < 4; nf++) {
      const int d = nf * 16 + r;
      const float sd = ehs[d];
      #pragma unroll
      for (int jj = 0; jj < 4; jj++) {
        const int e = e0 + wave * 16 + (lane >> 4) * 4 + jj;
        ST[(cb * 128 + e) * 128 + d0 + d] = (bf16_t)(acc[nf][jj] * sd);
      }
    }
    #pragma unroll
    for (int nf = 0; nf < 4; nf++) {
      const float ev = ehs[nf * 16 + r];
      const float e2 = ev * ev;
      #pragma unroll
      for (int jj = 0; jj < 4; jj++) acc[nf][jj] *= e2;
    }
    #pragma unroll
    for (int ks = 0; ks < 2; ks++) {
      const bf16x8 a = *(const bf16x8*)&vt[wave * 16 + r][ks * 32 + ko];
      #pragma unroll
      for (int nf = 0; nf < 4; nf++) {
        const bf16x8 bfr = *(const bf16x8*)&kgt[nf * 16 + r][ks * 32 + ko];
        acc[nf] = MFMA16(a, bfr, acc[nf]);
      }
    }
    __syncthreads();
  }
}

// ---------------------------------------------------------------------------
// chunk2: per (b,h,c): A = qg2 @ kd2^T (tril) -> P ; o = P@v + qg2@ST'
// ---------------------------------------------------------------------------
__global__ __launch_bounds__(256)
void chunk2_kernel(const bf16_t* __restrict__ qb, const bf16_t* __restrict__ kb,
                   const bf16_t* __restrict__ vb, const bf16_t* __restrict__ ST,
                   bf16_t* __restrict__ o16)
{
  __shared__ __align__(16) bf16_t qgs[64][136];
  __shared__ __align__(16) bf16_t kds[64][136];
  __shared__ __align__(16) bf16_t vTs[128][72];
  __shared__ __align__(16) bf16_t Ps[64][72];
  const int blk = blockIdx.x;
  const int c = blk & 31, h = (blk >> 5) & 15, b = blk >> 9;
  const size_t row0 = (size_t)b * 2048 + (size_t)c * 64;
  const int col0 = h * 128;
  const int tt = threadIdx.x, wave = tt >> 6, lane = tt & 63;
  const int r = lane & 15, ko = (lane >> 4) * 8;

  #pragma unroll
  for (int s = 0; s < 4; s++) {
    const int u = tt + s * 256;
    const int t = u >> 4, d8 = (u & 15) * 8;
    *(bf16x8*)&qgs[t][d8] = *(const bf16x8*)(qb + (row0 + t) * 2048 + col0 + d8);
    *(bf16x8*)&kds[t][d8] = *(const bf16x8*)(kb + (row0 + t) * 2048 + col0 + d8);
  }
  #pragma unroll
  for (int s = 0; s < 4; s++) {
    const int u = tt + s * 256;
    const int t = u >> 4, e8 = (u & 15) * 8;
    const bf16x8 vv = *(const bf16x8*)(vb + (row0 + t) * 2048 + col0 + e8);
    #pragma unroll
    for (int j = 0; j < 8; j++) vTs[e8 + j][t] = vv[j];
  }
  __syncthreads();

  bf16x8 aq[4];
  #pragma unroll
  for (int ks = 0; ks < 4; ks++) aq[ks] = *(const bf16x8*)&qgs[wave * 16 + r][ks * 32 + ko];

  f32x4 accA[4] = {};
  #pragma unroll
  for (int ks = 0; ks < 4; ks++)
    #pragma unroll
    for (int sf = 0; sf < 4; sf++) {
      const bf16x8 bfr = *(const bf16x8*)&kds[sf * 16 + r][ks * 32 + ko];
      accA[sf] = MFMA16(aq[ks], bfr, accA[sf]);
    }

  #pragma unroll
  for (int sf = 0; sf < 4; sf++)
    #pragma unroll
    for (int jj = 0; jj < 4; jj++) {
      const int t = wave * 16 + (lane >> 4) * 4 + jj;
      const int s = sf * 16 + r;
      Ps[t][s] = (bf16_t)(t >= s ? accA[sf][jj] : 0.0f);
    }

  f32x4 acc[8] = {};
  const size_t stbase = (size_t)blk * 128 * 128;
  #pragma unroll
  for (int ks = 0; ks < 4; ks++)
    #pragma unroll
    for (int ne = 0; ne < 8; ne++) {
      const bf16x8 bfr = *(const bf16x8*)(ST + stbase + (size_t)(ne * 16 + r) * 128 + ks * 32 + ko);
      acc[ne] = MFMA16(aq[ks], bfr, acc[ne]);
    }
  #pragma unroll
  for (int ks = 0; ks < 2; ks++) {
    const bf16x8 pa = *(const bf16x8*)&Ps[wave * 16 + r][ks * 32 + ko];
    #pragma unroll
    for (int ne = 0; ne < 8; ne++) {
      const bf16x8 bfr = *(const bf16x8*)&vTs[ne * 16 + r][ks * 32 + ko];
      acc[ne] = MFMA16(pa, bfr, acc[ne]);
    }
  }

  #pragma unroll
  for (int ne = 0; ne < 8; ne++)
    #pragma unroll
    for (int jj = 0; jj < 4; jj++) {
      const int t = wave * 16 + (lane >> 4) * 4 + jj;
      const int e = ne * 16 + r;
      o16[(row0 + t) * 2048 + col0 + e] = (bf16_t)acc[ne][jj];
    }
}

// ---------------------------------------------------------------------------
// RMSNorm over D=2048, bf16 in -> bf16 out
// ---------------------------------------------------------------------------
__global__ __launch_bounds__(256)
void rmsb_kernel(const bf16_t* __restrict__ o16, const float* __restrict__ w,
                 bf16_t* __restrict__ ob)
{
  __shared__ float red[4];
  const size_t row = blockIdx.x;
  const int tt = threadIdx.x;
  const bf16x8 v = *(const bf16x8*)(o16 + row * 2048 + tt * 8);
  float f[8], ss = 0.0f;
  #pragma unroll
  for (int j = 0; j < 8; j++) { f[j] = (float)v[j]; ss += f[j] * f[j]; }
  #pragma unroll
  for (int off = 32; off > 0; off >>= 1) ss += __shfl_down(ss, off);
  if ((tt & 63) == 0) red[tt >> 6] = ss;
  __syncthreads();
  const float inv = rsqrtf((red[0] + red[1] + red[2] + red[3]) * (1.0f / 2048.0f) + 1e-5f);
  const float4 w0 = *(const float4*)(w + tt * 8);
  const float4 w1 = *(const float4*)(w + tt * 8 + 4);
  bf16x8 o;
  o[0] = (bf16_t)(f[0] * inv * w0.x); o[1] = (bf16_t)(f[1] * inv * w0.y);
  o[2] = (bf16_t)(f[2] * inv * w0.z); o[3] = (bf16_t)(f[3] * inv * w0.w);
  o[4] = (bf16_t)(f[4] * inv * w1.x); o[5] = (bf16_t)(f[5] * inv * w1.y);
  o[6] = (bf16_t)(f[6] * inv * w1.z); o[7] = (bf16_t)(f[7] * inv * w1.w);
  *(bf16x8*)(ob + row * 2048 + tt * 8) = o;
}

// ---------------------------------------------------------------------------
extern "C" void kernel_launch(void* const* d_in, const int* in_sizes, int n_in,
                              void* d_out, int out_size, void* d_ws, size_t ws_size,
                              hipStream_t stream)
{
  const float* x  = (const float*)d_in[0];
  const float* Wq = (const float*)d_in[1];
  const float* Wf = (const float*)d_in[2];
  const float* Wi = (const float*)d_in[3];
  const float* Wo = (const float*)d_in[4];
  const float* gw = (const float*)d_in[5];
  float* out = (float*)d_out;
  char* ws = (char*)d_ws;

  const int K = 2048;
  const size_t MB = 1ull << 20;
  const int LDS = 131072;

  (void)hipFuncSetAttribute((const void*)gemm256<0>,
      hipFuncAttributeMaxDynamicSharedMemorySize, LDS);
  (void)hipFuncSetAttribute((const void*)gemm256<1>,
      hipFuncAttributeMaxDynamicSharedMemorySize, LDS);

  auto run = [&](const float* xs, float* outs, int nbs) {
    const int Ms = nbs * 2048;
    const size_t Sx = (size_t)Ms * 2048 * 2;     // bf16 matrix bytes
    bf16_t* xb  = (bf16_t*)(ws + 0);
    bf16_t* qb  = (bf16_t*)(ws + Sx);
    bf16_t* kb  = (bf16_t*)(ws + 2 * Sx);
    bf16_t* vb  = (bf16_t*)(ws + 3 * Sx);
    float*  g32 = (float*) (ws + 4 * Sx);        // 2*Sx bytes
    bf16_t* Wb  = (bf16_t*)(ws + 6 * Sx);        // 24 MiB (QKV fused / Wo)
    float*  egh = (float*) (ws + 6 * Sx + 24 * MB);
    bf16_t* STp = (bf16_t*)(ws + 4 * Sx);        // alias g32 (dead after prep)
    bf16_t* o16 = (bf16_t*)(ws + 0);             // alias xb  (dead after QKV gemm)
    bf16_t* ob  = (bf16_t*)(ws + Sx);            // alias qb  (dead after chunk)

    const int n8x = Ms * 2048 / 8;
    const int n8w = 2048 * 2048 / 8;

    f2b_kernel<<<(n8x + 255) / 256, 256, 0, stream>>>(xs, xb, n8x);
    f2b_kernel<<<(n8w + 255) / 256, 256, 0, stream>>>(Wq, Wb, n8w);
    f2b_kernel<<<(n8w + 255) / 256, 256, 0, stream>>>(Wf, Wb + 4194304, n8w);
    f2b_kernel<<<(n8w + 255) / 256, 256, 0, stream>>>(Wi, Wb + 8388608, n8w);

    gemm256<0><<<(Ms / 256) * (6144 / 256), 512, LDS, stream>>>(
        xb, Wb, qb, kb, vb, g32, nullptr, Ms, 6144, K);

    prep2_kernel<<<nbs * 512, 256, 0, stream>>>(qb, kb, g32, egh);
    state2_kernel<<<nbs * 64, 256, 0, stream>>>(kb, vb, egh, STp);
    chunk2_kernel<<<nbs * 512, 256, 0, stream>>>(qb, kb, vb, STp, o16);
    rmsb_kernel<<<Ms, 256, 0, stream>>>(o16, gw, ob);

    f2b_kernel<<<(n8w + 255) / 256, 256, 0, stream>>>(Wo, Wb, n8w);
    gemm256<1><<<(Ms / 256) * (2048 / 256), 512, LDS, stream>>>(
        ob, Wb, nullptr, nullptr, nullptr, nullptr, outs, Ms, 2048, K);
  };

  const size_t Sx_full = (size_t)8192 * 2048 * 2;
  const size_t need_full = 6 * Sx_full + 24 * MB + 2048 * 128 * 4;
  if (ws_size >= need_full) {
    run(x, out, 4);
  } else {
    for (int sb = 0; sb < 4; sb++)
      run(x + (size_t)sb * 2048 * 2048, out + (size_t)sb * 2048 * 2048, 1);
  }

  (void)in_sizes; (void)n_in; (void)out_size;
}